// Round 1
// baseline (455.857 us; speedup 1.0000x reference)
//
#include <hip/hip_runtime.h>
#include <math.h>

#define BATCH 4096
#define NROWS (2 * BATCH)      // 8192
#define D 128
#define DX 512

constexpr int NSPLIT = 8;
constexpr int COLS_PER_SPLIT = NROWS / NSPLIT;  // 1024
constexpr int RT = 32;   // rows per block
constexpr int CT = 64;   // cols per tile

// ws float layout
#define WS_RECON 0
#define WS_ZREC  1
#define WS_POS   2
#define WS_LSE   3
#define WS_INVN  16
#define WS_PART  (16 + NROWS)
// total floats needed: 16 + 8192 + 8192*NSPLIT = 73744 (~295 KB)

__global__ void k_init(float* ws) {
    if (threadIdx.x < 16) ws[threadIdx.x] = 0.0f;
}

__device__ __forceinline__ float wave_reduce(float v) {
    #pragma unroll
    for (int o = 32; o > 0; o >>= 1) v += __shfl_xor(v, o);
    return v;
}

// one wave per row: inv-norm
__global__ void k_norms(const float* __restrict__ rep, float* __restrict__ ws) {
    const int wave = threadIdx.x >> 6, lane = threadIdx.x & 63;
    const int row = blockIdx.x * 4 + wave;
    float2 v = *reinterpret_cast<const float2*>(rep + row * D + lane * 2);
    float s = wave_reduce(v.x * v.x + v.y * v.y);
    if (lane == 0) ws[WS_INVN + row] = 1.0f / (sqrtf(s) + 1e-8f);
}

__global__ void k_recon(const float4* __restrict__ xr, const float4* __restrict__ xo,
                        float* __restrict__ ws) {
    const int n4 = NROWS * DX / 4;
    float s = 0.f;
    for (int i = blockIdx.x * blockDim.x + threadIdx.x; i < n4;
         i += gridDim.x * blockDim.x) {
        float4 a = xr[i], b = xo[i];
        float dx = a.x - b.x, dy = a.y - b.y, dz = a.z - b.z, dw = a.w - b.w;
        s += dx * dx + dy * dy + dz * dz + dw * dw;
    }
    s = wave_reduce(s);
    __shared__ float sh[4];
    const int wave = threadIdx.x >> 6, lane = threadIdx.x & 63;
    if (lane == 0) sh[wave] = s;
    __syncthreads();
    if (threadIdx.x == 0) atomicAdd(&ws[WS_RECON], sh[0] + sh[1] + sh[2] + sh[3]);
}

__global__ void k_zrecon(const float4* __restrict__ rep4, float* __restrict__ ws) {
    const int n4 = BATCH * D / 4;   // 131072
    const float4* zi = rep4;
    const float4* zj = rep4 + n4;
    int i = blockIdx.x * blockDim.x + threadIdx.x;
    float s = 0.f;
    if (i < n4) {
        float4 a = zi[i], b = zj[i];
        float dx = a.x - b.x, dy = a.y - b.y, dz = a.z - b.z, dw = a.w - b.w;
        s = dx * dx + dy * dy + dz * dz + dw * dw;
    }
    s = wave_reduce(s);
    __shared__ float sh[4];
    const int wave = threadIdx.x >> 6, lane = threadIdx.x & 63;
    if (lane == 0) sh[wave] = s;
    __syncthreads();
    if (threadIdx.x == 0) atomicAdd(&ws[WS_ZREC], sh[0] + sh[1] + sh[2] + sh[3]);
}

// sum of positives over all 2B rows = 4 * sum_{i<B} dot(n_i, n_{i+B})
__global__ void k_pos(const float* __restrict__ rep, float* __restrict__ ws) {
    const int wave = threadIdx.x >> 6, lane = threadIdx.x & 63;
    const int i = blockIdx.x * 4 + wave;          // 0..4095
    float2 a = *reinterpret_cast<const float2*>(rep + i * D + lane * 2);
    float2 b = *reinterpret_cast<const float2*>(rep + (i + BATCH) * D + lane * 2);
    float s = wave_reduce(a.x * b.x + a.y * b.y);
    if (lane == 0)
        atomicAdd(&ws[WS_POS], 4.0f * s * ws[WS_INVN + i] * ws[WS_INVN + i + BATCH]);
}

// main: per-row sum of exp(sim) excluding diagonal, partial per column-split.
// A-tile holds 2*n_i (temperature folded in), B-tile holds n_j.
// k-major swizzled LDS: As[k][32], Bs[k][64], XOR chunk swizzle.
__global__ __launch_bounds__(128) void k_lse(const float* __restrict__ rep,
                                             float* __restrict__ ws) {
    __shared__ float As[D * RT];          // 16 KB
    __shared__ float Bs[D * CT];          // 32 KB
    __shared__ float red[RT][17];         // ~2 KB

    const int tid = threadIdx.x;
    const int ty = tid >> 4;              // 0..7  (4 rows each)
    const int tx = tid & 15;              // 0..15 (4 cols each)
    const int row0 = blockIdx.x * RT;
    const int split = blockIdx.y;
    const float* __restrict__ invn = ws + WS_INVN;

    // ---- stage A (once): transpose to k-major, swizzled, scaled by 2*invn
    #pragma unroll
    for (int p = 0; p < 8; ++p) {
        int flat = p * 128 + tid;
        int r = flat >> 5;                // 0..31
        int q = flat & 31;                // float4 index along k
        float4 v = *reinterpret_cast<const float4*>(rep + (row0 + r) * D + q * 4);
        float sc = 2.0f * invn[row0 + r];
        int swz = (r >> 2) ^ (q & 7);     // (k>>2)&7 == q
        int base = 4 * swz + (r & 3);
        As[(q * 4 + 0) * RT + base] = v.x * sc;
        As[(q * 4 + 1) * RT + base] = v.y * sc;
        As[(q * 4 + 2) * RT + base] = v.z * sc;
        As[(q * 4 + 3) * RT + base] = v.w * sc;
    }

    float sumexp[4] = {0.f, 0.f, 0.f, 0.f};
    const int c_base = split * COLS_PER_SPLIT;

    for (int ctile = 0; ctile < COLS_PER_SPLIT / CT; ++ctile) {   // 16 tiles
        const int c0 = c_base + ctile * CT;
        __syncthreads();   // prior readers of Bs done (also fences As on iter 0)

        // ---- stage B tile: k-major, swizzled, scaled by invn
        #pragma unroll
        for (int p = 0; p < 16; ++p) {
            int flat = p * 128 + tid;
            int c = flat >> 5;            // 0..63
            int q = flat & 31;
            float4 v = *reinterpret_cast<const float4*>(rep + (c0 + c) * D + q * 4);
            float sc = invn[c0 + c];
            int swz = (c >> 2) ^ ((q >> 1) & 15);   // (k>>3)&15 == q>>1
            int base = 4 * swz + (c & 3);
            Bs[(q * 4 + 0) * CT + base] = v.x * sc;
            Bs[(q * 4 + 1) * CT + base] = v.y * sc;
            Bs[(q * 4 + 2) * CT + base] = v.z * sc;
            Bs[(q * 4 + 3) * CT + base] = v.w * sc;
        }
        __syncthreads();

        // ---- 32x64 tile of sim = (2 n_i) . (n_j)
        float acc[4][4] = {};
        #pragma unroll 4
        for (int k = 0; k < D; ++k) {
            float4 a = *reinterpret_cast<const float4*>(
                &As[k * RT + 4 * (ty ^ ((k >> 2) & 7))]);
            float4 b = *reinterpret_cast<const float4*>(
                &Bs[k * CT + 4 * (tx ^ ((k >> 3) & 15))]);
            acc[0][0] += a.x * b.x; acc[0][1] += a.x * b.y;
            acc[0][2] += a.x * b.z; acc[0][3] += a.x * b.w;
            acc[1][0] += a.y * b.x; acc[1][1] += a.y * b.y;
            acc[1][2] += a.y * b.z; acc[1][3] += a.y * b.w;
            acc[2][0] += a.z * b.x; acc[2][1] += a.z * b.y;
            acc[2][2] += a.z * b.z; acc[2][3] += a.z * b.w;
            acc[3][0] += a.w * b.x; acc[3][1] += a.w * b.y;
            acc[3][2] += a.w * b.z; acc[3][3] += a.w * b.w;
        }

        // ---- accumulate exp, excluding main diagonal
        #pragma unroll
        for (int rr = 0; rr < 4; ++rr) {
            const int gi = row0 + 4 * ty + rr;
            #pragma unroll
            for (int cc = 0; cc < 4; ++cc) {
                const int gj = c0 + 4 * tx + cc;
                float e = __expf(acc[rr][cc]);
                sumexp[rr] += (gj == gi) ? 0.f : e;
            }
        }
    }

    // ---- reduce the 16 tx-partials per row, store per-split partial
    #pragma unroll
    for (int rr = 0; rr < 4; ++rr) red[4 * ty + rr][tx] = sumexp[rr];
    __syncthreads();
    if (tid < RT) {
        float s = 0.f;
        #pragma unroll
        for (int t = 0; t < 16; ++t) s += red[tid][t];
        ws[WS_PART + (row0 + tid) * NSPLIT + split] = s;
    }
}

// sum_i log(sum of split partials)
__global__ void k_lse_reduce(float* __restrict__ ws) {
    const int i = blockIdx.x * blockDim.x + threadIdx.x;   // 8192 threads
    float lse = 0.f;
    if (i < NROWS) {
        float s = 0.f;
        #pragma unroll
        for (int t = 0; t < NSPLIT; ++t) s += ws[WS_PART + i * NSPLIT + t];
        lse = logf(s);
    }
    lse = wave_reduce(lse);
    __shared__ float sh[4];
    const int wave = threadIdx.x >> 6, lane = threadIdx.x & 63;
    if (lane == 0) sh[wave] = lse;
    __syncthreads();
    if (threadIdx.x == 0) atomicAdd(&ws[WS_LSE], sh[0] + sh[1] + sh[2] + sh[3]);
}

__global__ void k_combine(const float* __restrict__ ws, float* __restrict__ out) {
    float recon  = ws[WS_RECON] / (float)(NROWS * DX);
    float zrecon = ws[WS_ZREC]  / (float)(BATCH * D);
    float closs  = (ws[WS_LSE] - ws[WS_POS]) / (float)NROWS;
    out[0] = recon + closs + zrecon;
    out[1] = closs;
    out[2] = recon;
    out[3] = zrecon;
}

extern "C" void kernel_launch(void* const* d_in, const int* in_sizes, int n_in,
                              void* d_out, int out_size, void* d_ws, size_t ws_size,
                              hipStream_t stream) {
    const float* rep = (const float*)d_in[0];
    const float4* xr = (const float4*)d_in[1];
    const float4* xo = (const float4*)d_in[2];
    float* out = (float*)d_out;
    float* ws = (float*)d_ws;

    k_init<<<1, 64, 0, stream>>>(ws);
    k_norms<<<NROWS / 4, 256, 0, stream>>>(rep, ws);
    k_recon<<<1024, 256, 0, stream>>>(xr, xo, ws);
    k_zrecon<<<BATCH * D / 4 / 256, 256, 0, stream>>>((const float4*)rep, ws);
    k_pos<<<BATCH / 4, 256, 0, stream>>>(rep, ws);

    dim3 grid(NROWS / RT, NSPLIT);
    k_lse<<<grid, 128, 0, stream>>>(rep, ws);

    k_lse_reduce<<<NROWS / 256, 256, 0, stream>>>(ws);
    k_combine<<<1, 1, 0, stream>>>(ws, out);
}

// Round 2
// 122.220 us; speedup vs baseline: 3.7298x; 3.7298x over previous
//
#include <hip/hip_runtime.h>
#include <math.h>

#define BATCH 4096
#define NROWS (2 * BATCH)      // 8192
#define D 128
#define DX 512

constexpr int NSPLIT = 8;
constexpr int RTILE = 128;                 // rows per block
constexpr int CT = 128;                    // cols per tile
constexpr int NT = NROWS / NSPLIT / CT;    // 8 col tiles per split

// ws float layout
#define WS_RECON 0
#define WS_ZREC  1
#define WS_POS   2
#define WS_LSE   3
#define WS_INVN  16
#define WS_PART  (16 + NROWS)                    // [row][NSPLIT]
#define WS_NBF   (WS_PART + NROWS * NSPLIT)      // __bf16[NROWS][D] after this

typedef __bf16 bf16x8 __attribute__((ext_vector_type(8)));
typedef __bf16 bf16x2 __attribute__((ext_vector_type(2)));
typedef float  f32x16 __attribute__((ext_vector_type(16)));
typedef unsigned int u32;

__device__ __forceinline__ void gload_lds16(const void* g, void* l) {
    __builtin_amdgcn_global_load_lds(
        (const __attribute__((address_space(1))) u32*)g,
        (__attribute__((address_space(3))) u32*)l, 16, 0, 0);
}

__global__ void k_init(float* ws) {
    if (threadIdx.x < 16) ws[threadIdx.x] = 0.0f;
}

__device__ __forceinline__ float wave_reduce(float v) {
    #pragma unroll
    for (int o = 32; o > 0; o >>= 1) v += __shfl_xor(v, o);
    return v;
}

// one wave per row: inv-norm + bf16 normalized copy
__global__ void k_norms(const float* __restrict__ rep, float* __restrict__ ws) {
    const int wave = threadIdx.x >> 6, lane = threadIdx.x & 63;
    const int row = blockIdx.x * 4 + wave;
    float2 v = *reinterpret_cast<const float2*>(rep + row * D + lane * 2);
    float s = wave_reduce(v.x * v.x + v.y * v.y);
    float inv = 1.0f / (sqrtf(s) + 1e-8f);
    if (lane == 0) ws[WS_INVN + row] = inv;
    __bf16* nbf = (__bf16*)(ws + WS_NBF);
    bf16x2 p;
    p.x = (__bf16)(v.x * inv);
    p.y = (__bf16)(v.y * inv);
    *reinterpret_cast<bf16x2*>(nbf + row * D + lane * 2) = p;
}

__global__ void k_recon(const float4* __restrict__ xr, const float4* __restrict__ xo,
                        float* __restrict__ ws) {
    const int n4 = NROWS * DX / 4;
    float s = 0.f;
    for (int i = blockIdx.x * blockDim.x + threadIdx.x; i < n4;
         i += gridDim.x * blockDim.x) {
        float4 a = xr[i], b = xo[i];
        float dx = a.x - b.x, dy = a.y - b.y, dz = a.z - b.z, dw = a.w - b.w;
        s += dx * dx + dy * dy + dz * dz + dw * dw;
    }
    s = wave_reduce(s);
    __shared__ float sh[4];
    const int wave = threadIdx.x >> 6, lane = threadIdx.x & 63;
    if (lane == 0) sh[wave] = s;
    __syncthreads();
    if (threadIdx.x == 0) atomicAdd(&ws[WS_RECON], sh[0] + sh[1] + sh[2] + sh[3]);
}

__global__ void k_zrecon(const float4* __restrict__ rep4, float* __restrict__ ws) {
    const int n4 = BATCH * D / 4;   // 131072
    const float4* zi = rep4;
    const float4* zj = rep4 + n4;
    int i = blockIdx.x * blockDim.x + threadIdx.x;
    float s = 0.f;
    if (i < n4) {
        float4 a = zi[i], b = zj[i];
        float dx = a.x - b.x, dy = a.y - b.y, dz = a.z - b.z, dw = a.w - b.w;
        s = dx * dx + dy * dy + dz * dz + dw * dw;
    }
    s = wave_reduce(s);
    __shared__ float sh[4];
    const int wave = threadIdx.x >> 6, lane = threadIdx.x & 63;
    if (lane == 0) sh[wave] = s;
    __syncthreads();
    if (threadIdx.x == 0) atomicAdd(&ws[WS_ZREC], sh[0] + sh[1] + sh[2] + sh[3]);
}

// sum of positives = 4 * sum_{i<B} dot(n_i, n_{i+B})   (f32 path)
__global__ void k_pos(const float* __restrict__ rep, float* __restrict__ ws) {
    const int wave = threadIdx.x >> 6, lane = threadIdx.x & 63;
    const int i = blockIdx.x * 4 + wave;          // 0..4095
    float2 a = *reinterpret_cast<const float2*>(rep + i * D + lane * 2);
    float2 b = *reinterpret_cast<const float2*>(rep + (i + BATCH) * D + lane * 2);
    float s = wave_reduce(a.x * b.x + a.y * b.y);
    if (lane == 0)
        atomicAdd(&ws[WS_POS], 4.0f * s * ws[WS_INVN + i] * ws[WS_INVN + i + BATCH]);
}

// MFMA Gram + fused exp-rowsum. 128x128 tile/block; 4 waves, each 32 rows x 128 cols.
// A frags in registers; B double-buffered in LDS via global_load_lds with
// pre-swizzled global source (chunk ^= row&15); linear LDS dest.
__global__ __launch_bounds__(256, 2) void k_lse(float* __restrict__ ws) {
    __shared__ __bf16 buf[2][RTILE * D];           // 2 x 32 KB
    const __bf16* __restrict__ nbf = (const __bf16*)(ws + WS_NBF);

    const int tid = threadIdx.x;
    const int w = tid >> 6, l = tid & 63;
    const int R0 = blockIdx.x * RTILE;
    const int split = blockIdx.y;
    const int C_base = split * (NT * CT);

    // wave w stages rows [w*32, w*32+32) of a 128x128 bf16 tile
    auto stage = [&](int bufi, int grow0) {
        #pragma unroll
        for (int q = 0; q < 8; ++q) {
            const int lr = w * 32 + q * 4 + (l >> 4);       // local row 0..127
            const int schunk = (l & 15) ^ (lr & 15);        // swizzled src chunk
            const __bf16* src = nbf + (grow0 + lr) * D + schunk * 8;
            gload_lds16(src, &buf[bufi][(w * 32 + q * 4) * D]);
        }
    };

    // ---- stage A, load A fragments to registers
    stage(0, R0);
    __syncthreads();

    bf16x8 afrag[8];
    {
        const int lr = w * 32 + (l & 31);
        const int xw = lr & 15;
        #pragma unroll
        for (int s = 0; s < 8; ++s) {
            const int c = 2 * s + (l >> 5);
            afrag[s] = *reinterpret_cast<const bf16x8*>(&buf[0][lr * D + (c ^ xw) * 8]);
        }
    }

    stage(1, C_base);        // B tile 0 (buf0 safe: afrag reads drain before barrier)
    __syncthreads();

    float sumexp[16] = {};

    for (int t = 0; t < NT; ++t) {
        const int cur = 1 - (t & 1);                 // buffer holding tile t
        if (t + 1 < NT) stage(t & 1, C_base + (t + 1) * CT);

        f32x16 acc[4] = {};
        const __bf16* bb = &buf[cur][0];
        const int xl = l & 15;
        #pragma unroll
        for (int s = 0; s < 8; ++s) {
            const int c = 2 * s + (l >> 5);
            #pragma unroll
            for (int cb = 0; cb < 4; ++cb) {
                const int lc = cb * 32 + (l & 31);
                bf16x8 bfr = *reinterpret_cast<const bf16x8*>(
                    &bb[lc * D + (c ^ xl) * 8]);
                acc[cb] = __builtin_amdgcn_mfma_f32_32x32x16_bf16(
                    afrag[s], bfr, acc[cb], 0, 0, 0);
            }
        }

        // exp + accumulate row partials (sim = dot/T = 2*dot; |2*dot| <= ~2)
        const bool diag = (C_base + t * CT == R0);
        #pragma unroll
        for (int cb = 0; cb < 4; ++cb) {
            #pragma unroll
            for (int r = 0; r < 16; ++r) {
                float e = __expf(acc[cb][r] * 2.0f);
                if (diag && cb == w) {
                    const int rrow = (r & 3) + 8 * (r >> 2) + 4 * (l >> 5);
                    if (rrow == (l & 31)) e = 0.0f;
                }
                sumexp[r] += e;
            }
        }
        __syncthreads();
    }

    // ---- reduce across the 32 column-lanes; lanes 0 and 32 hold row sums
    #pragma unroll
    for (int r = 0; r < 16; ++r) {
        float v = sumexp[r];
        #pragma unroll
        for (int m = 1; m <= 16; m <<= 1) v += __shfl_xor(v, m);
        sumexp[r] = v;
    }
    if ((l & 31) == 0) {
        #pragma unroll
        for (int r = 0; r < 16; ++r) {
            const int row = R0 + w * 32 + (r & 3) + 8 * (r >> 2) + 4 * (l >> 5);
            ws[WS_PART + row * NSPLIT + split] = sumexp[r];
        }
    }
}

// sum_i log(sum of split partials)
__global__ void k_lse_reduce(float* __restrict__ ws) {
    const int i = blockIdx.x * blockDim.x + threadIdx.x;   // 8192 threads
    float lse = 0.f;
    if (i < NROWS) {
        float s = 0.f;
        #pragma unroll
        for (int t = 0; t < NSPLIT; ++t) s += ws[WS_PART + i * NSPLIT + t];
        lse = logf(s);
    }
    lse = wave_reduce(lse);
    __shared__ float sh[4];
    const int wave = threadIdx.x >> 6, lane = threadIdx.x & 63;
    if (lane == 0) sh[wave] = lse;
    __syncthreads();
    if (threadIdx.x == 0) atomicAdd(&ws[WS_LSE], sh[0] + sh[1] + sh[2] + sh[3]);
}

__global__ void k_combine(const float* __restrict__ ws, float* __restrict__ out) {
    float recon  = ws[WS_RECON] / (float)(NROWS * DX);
    float zrecon = ws[WS_ZREC]  / (float)(BATCH * D);
    float closs  = (ws[WS_LSE] - ws[WS_POS]) / (float)NROWS;
    out[0] = recon + closs + zrecon;
    out[1] = closs;
    out[2] = recon;
    out[3] = zrecon;
}

extern "C" void kernel_launch(void* const* d_in, const int* in_sizes, int n_in,
                              void* d_out, int out_size, void* d_ws, size_t ws_size,
                              hipStream_t stream) {
    const float* rep = (const float*)d_in[0];
    const float4* xr = (const float4*)d_in[1];
    const float4* xo = (const float4*)d_in[2];
    float* out = (float*)d_out;
    float* ws = (float*)d_ws;

    k_init<<<1, 64, 0, stream>>>(ws);
    k_norms<<<NROWS / 4, 256, 0, stream>>>(rep, ws);
    k_recon<<<1024, 256, 0, stream>>>(xr, xo, ws);
    k_zrecon<<<BATCH * D / 4 / 256, 256, 0, stream>>>((const float4*)rep, ws);
    k_pos<<<BATCH / 4, 256, 0, stream>>>(rep, ws);

    dim3 grid(NROWS / RTILE, NSPLIT);
    k_lse<<<grid, 256, 0, stream>>>(ws);

    k_lse_reduce<<<NROWS / 256, 256, 0, stream>>>(ws);
    k_combine<<<1, 1, 0, stream>>>(ws, out);
}

// Round 3
// 44.473 us; speedup vs baseline: 10.2502x; 2.7482x over previous
//
#include <hip/hip_runtime.h>
#include <math.h>

#define BATCH 4096
#define NROWS (2 * BATCH)      // 8192
#define D 128
#define DX 512

constexpr int NSPLIT = 8;
constexpr int RTILE = 128;                 // rows per block
constexpr int CT = 128;                    // cols per tile
constexpr int NT = NROWS / NSPLIT / CT;    // 8 col tiles per split

// sqrt(2*log2(e)) — both Gram operands carry this, so dot == log2(exp(sim))
#define SCALE 1.698644f

// ws float layout (no atomics anywhere; every slot written every call)
#define WS_PART   0                          // [NROWS][NSPLIT]
#define WS_RECONP 65536                      // [512]
#define WS_ZRECP  (WS_RECONP + 512)          // [256]
#define WS_POSP   (WS_ZRECP + 256)           // [256]
#define WS_NBF    (WS_POSP + 256)            // __bf16[NROWS][D], 16B-aligned

typedef __bf16 bf16x8 __attribute__((ext_vector_type(8)));
typedef __bf16 bf16x2 __attribute__((ext_vector_type(2)));
typedef float  f32x16 __attribute__((ext_vector_type(16)));
typedef unsigned int u32;

__device__ __forceinline__ void gload_lds16(const void* g, void* l) {
    __builtin_amdgcn_global_load_lds(
        (const __attribute__((address_space(1))) u32*)g,
        (__attribute__((address_space(3))) u32*)l, 16, 0, 0);
}

__device__ __forceinline__ float wave_reduce(float v) {
    #pragma unroll
    for (int o = 32; o > 0; o >>= 1) v += __shfl_xor(v, o);
    return v;
}

// one wave per (i, i+B) pair: norms, scaled-bf16 rows, zrecon & positives partials
__global__ __launch_bounds__(256) void k_prep(const float* __restrict__ rep,
                                              float* __restrict__ ws) {
    const int w = threadIdx.x >> 6, l = threadIdx.x & 63;
    const int wg = blockIdx.x * 4 + w;          // 0..1023
    __bf16* nbf = (__bf16*)(ws + WS_NBF);
    float zacc = 0.f, pacc = 0.f;
    #pragma unroll
    for (int p = 0; p < 4; ++p) {
        const int i = wg + p * 1024;            // 0..4095
        float2 a = *reinterpret_cast<const float2*>(rep + i * D + l * 2);
        float2 b = *reinterpret_cast<const float2*>(rep + (i + BATCH) * D + l * 2);
        float dx = a.x - b.x, dy = a.y - b.y;
        float sa  = wave_reduce(a.x * a.x + a.y * a.y);
        float sb  = wave_reduce(b.x * b.x + b.y * b.y);
        float sab = wave_reduce(a.x * b.x + a.y * b.y);
        float sd  = wave_reduce(dx * dx + dy * dy);
        float ia = 1.0f / (sqrtf(sa) + 1e-8f);
        float ib = 1.0f / (sqrtf(sb) + 1e-8f);
        zacc += sd;
        pacc += sab * ia * ib;
        bf16x2 pa, pb;
        pa.x = (__bf16)(a.x * ia * SCALE); pa.y = (__bf16)(a.y * ia * SCALE);
        pb.x = (__bf16)(b.x * ib * SCALE); pb.y = (__bf16)(b.y * ib * SCALE);
        *reinterpret_cast<bf16x2*>(nbf + i * D + l * 2) = pa;
        *reinterpret_cast<bf16x2*>(nbf + (i + BATCH) * D + l * 2) = pb;
    }
    __shared__ float shz[4], shp[4];
    if (l == 0) { shz[w] = zacc; shp[w] = pacc; }
    __syncthreads();
    if (threadIdx.x == 0) {
        ws[WS_ZRECP + blockIdx.x] = shz[0] + shz[1] + shz[2] + shz[3];
        ws[WS_POSP + blockIdx.x] = 4.0f * (shp[0] + shp[1] + shp[2] + shp[3]);
    }
}

// MFMA Gram + fused exp2-rowsum + fused xrecon-MSE partial.
// 128x128 tile/block; A frags in registers; B double-buffered via
// global_load_lds with pre-swizzled global source; linear LDS dest.
__global__ __launch_bounds__(256, 2) void k_lse(const float4* __restrict__ xr,
                                                const float4* __restrict__ xo,
                                                float* __restrict__ ws) {
    __shared__ __bf16 buf[2][RTILE * D];           // 2 x 32 KB
    const __bf16* __restrict__ nbf = (const __bf16*)(ws + WS_NBF);

    const int tid = threadIdx.x;
    const int w = tid >> 6, l = tid & 63;
    const int R0 = blockIdx.x * RTILE;
    const int split = blockIdx.y;
    const int C_base = split * (NT * CT);
    const int fid = blockIdx.x + gridDim.x * blockIdx.y;   // 0..511

    auto stage = [&](int bufi, int grow0) {
        #pragma unroll
        for (int q = 0; q < 8; ++q) {
            const int lr = w * 32 + q * 4 + (l >> 4);       // local row 0..127
            const int schunk = (l & 15) ^ (lr & 15);        // swizzled src chunk
            const __bf16* src = nbf + (grow0 + lr) * D + schunk * 8;
            gload_lds16(src, &buf[bufi][(w * 32 + q * 4) * D]);
        }
    };

    stage(0, R0);
    __syncthreads();

    bf16x8 afrag[8];
    {
        const int lr = w * 32 + (l & 31);
        const int xw = lr & 15;
        #pragma unroll
        for (int s = 0; s < 8; ++s) {
            const int c = 2 * s + (l >> 5);
            afrag[s] = *reinterpret_cast<const bf16x8*>(&buf[0][lr * D + (c ^ xw) * 8]);
        }
    }

    stage(1, C_base);        // B tile 0
    __syncthreads();

    float sumexp[16] = {};
    float racc = 0.f;

    for (int t = 0; t < NT; ++t) {
        const int cur = 1 - (t & 1);
        if (t + 1 < NT) stage(t & 1, C_base + (t + 1) * CT);

        // fused xrecon MSE: one float4-pair per thread per tile (latency hidden
        // under the MFMA block; bandwidth spread over the whole kernel)
        const int ridx = fid * 2048 + t * 256 + tid;
        float4 ra = xr[ridx], rb = xo[ridx];

        f32x16 acc[4] = {};
        const __bf16* bb = &buf[cur][0];
        const int xl = l & 15;
        #pragma unroll
        for (int s = 0; s < 8; ++s) {
            const int c = 2 * s + (l >> 5);
            #pragma unroll
            for (int cb = 0; cb < 4; ++cb) {
                const int lc = cb * 32 + (l & 31);
                bf16x8 bfr = *reinterpret_cast<const bf16x8*>(
                    &bb[lc * D + (c ^ xl) * 8]);
                acc[cb] = __builtin_amdgcn_mfma_f32_32x32x16_bf16(
                    afrag[s], bfr, acc[cb], 0, 0, 0);
            }
        }

        // acc == sim*log2(e) by operand scaling → exp(sim) = exp2(acc)
        const bool diag = (C_base + t * CT == R0);
        #pragma unroll
        for (int cb = 0; cb < 4; ++cb) {
            #pragma unroll
            for (int r = 0; r < 16; ++r) {
                float e = __builtin_amdgcn_exp2f(acc[cb][r]);
                if (diag && cb == w) {
                    const int rrow = (r & 3) + 8 * (r >> 2) + 4 * (l >> 5);
                    if (rrow == (l & 31)) e = 0.0f;
                }
                sumexp[r] += e;
            }
        }

        {
            float dx = ra.x - rb.x, dy = ra.y - rb.y;
            float dz = ra.z - rb.z, dw2 = ra.w - rb.w;
            racc += dx * dx + dy * dy + dz * dz + dw2 * dw2;
        }
        __syncthreads();
    }

    // reduce the 32 column-lanes; lanes 0 and 32 hold row sums
    #pragma unroll
    for (int r = 0; r < 16; ++r) {
        float v = sumexp[r];
        #pragma unroll
        for (int m = 1; m <= 16; m <<= 1) v += __shfl_xor(v, m);
        sumexp[r] = v;
    }
    if ((l & 31) == 0) {
        #pragma unroll
        for (int r = 0; r < 16; ++r) {
            const int row = R0 + w * 32 + (r & 3) + 8 * (r >> 2) + 4 * (l >> 5);
            ws[WS_PART + row * NSPLIT + split] = sumexp[r];
        }
    }

    // recon partial for this block
    racc = wave_reduce(racc);
    __shared__ float shr[4];
    if (l == 0) shr[w] = racc;
    __syncthreads();
    if (tid == 0) ws[WS_RECONP + fid] = shr[0] + shr[1] + shr[2] + shr[3];
}

// single block: per-row log of summed split-partials + final combine
__global__ __launch_bounds__(256) void k_combine(const float* __restrict__ ws,
                                                 float* __restrict__ out) {
    const int tid = threadIdx.x;
    float lacc = 0.f;
    for (int i = tid; i < NROWS; i += 256) {
        float s = 0.f;
        #pragma unroll
        for (int t = 0; t < NSPLIT; ++t) s += ws[WS_PART + i * NSPLIT + t];
        lacc += logf(s);
    }
    float racc = ws[WS_RECONP + tid] + ws[WS_RECONP + 256 + tid];
    float zacc = ws[WS_ZRECP + tid];
    float pacc = ws[WS_POSP + tid];

    lacc = wave_reduce(lacc);
    racc = wave_reduce(racc);
    zacc = wave_reduce(zacc);
    pacc = wave_reduce(pacc);

    __shared__ float sh[4][4];
    const int w = tid >> 6, l = tid & 63;
    if (l == 0) { sh[0][w] = lacc; sh[1][w] = racc; sh[2][w] = zacc; sh[3][w] = pacc; }
    __syncthreads();
    if (tid == 0) {
        float lse = sh[0][0] + sh[0][1] + sh[0][2] + sh[0][3];
        float rec = (sh[1][0] + sh[1][1] + sh[1][2] + sh[1][3]) / (float)(NROWS * DX);
        float zre = (sh[2][0] + sh[2][1] + sh[2][2] + sh[2][3]) / (float)(BATCH * D);
        float pos = sh[3][0] + sh[3][1] + sh[3][2] + sh[3][3];
        float closs = (lse - pos) / (float)NROWS;
        out[0] = rec + closs + zre;
        out[1] = closs;
        out[2] = rec;
        out[3] = zre;
    }
}

extern "C" void kernel_launch(void* const* d_in, const int* in_sizes, int n_in,
                              void* d_out, int out_size, void* d_ws, size_t ws_size,
                              hipStream_t stream) {
    const float* rep = (const float*)d_in[0];
    const float4* xr = (const float4*)d_in[1];
    const float4* xo = (const float4*)d_in[2];
    float* out = (float*)d_out;
    float* ws = (float*)d_ws;

    k_prep<<<256, 256, 0, stream>>>(rep, ws);
    dim3 grid(NROWS / RTILE, NSPLIT);
    k_lse<<<grid, 256, 0, stream>>>(xr, xo, ws);
    k_combine<<<1, 256, 0, stream>>>(ws, out);
}